// Round 1
// baseline (234.777 us; speedup 1.0000x reference)
//
#include <hip/hip_runtime.h>

// ---------------------------------------------------------------------------
// Block-sparse linear  y = x @ W^T + bias  on MI355X (gfx950)
// x:[4096,4096] f32, blocks:[1024,64,64] f32, bias:[4096] f32,
// row_idx/col_idx:[1024] i32.  y:[4096,4096] f32.
//
// Strategy: convert x/blocks to bf16 once (RNE), build a deterministic CSR of
// blocks per output row-block, then an MFMA GEMM-ish kernel per
// (n-tile=256 rows, row-block) with global_load_lds(16B) staging and an XOR
// swizzle at 16B granularity to avoid LDS bank conflicts on ds_read_b128.
// ---------------------------------------------------------------------------

typedef __attribute__((ext_vector_type(8))) short bf16x8;   // MFMA A/B frag (4 VGPRs)
typedef __attribute__((ext_vector_type(8))) unsigned short u16x8;
typedef __attribute__((ext_vector_type(4))) float f32x4;     // MFMA C/D frag

#define N_ROWS 4096
#define IN_DIM 4096
#define OUT_DIM 4096
#define BS 64
#define K_BLOCKS 1024
#define NT 256   // rows per workgroup tile

// fp32 -> bf16 round-to-nearest-even
__device__ static inline unsigned short f2bf(float f) {
    unsigned u = __float_as_uint(f);
    u += 0x7FFFu + ((u >> 16) & 1u);
    return (unsigned short)(u >> 16);
}

__device__ static inline void async_copy16(const void* g, void* l) {
    __builtin_amdgcn_global_load_lds(
        (const __attribute__((address_space(1))) void*)g,
        (__attribute__((address_space(3))) void*)l, 16, 0, 0);
}

// --- prep: convert x (16777216 f32) and blocks (4194304 f32) to bf16 -------
__global__ void bsl_convert(const float* __restrict__ x,
                            const float* __restrict__ blocks,
                            unsigned short* __restrict__ xb,
                            unsigned short* __restrict__ bb) {
    long t = (long)blockIdx.x * 256 + threadIdx.x;   // 0 .. 2621439 (8 floats each)
    const float4* src;
    unsigned short* dst;
    long off4;
    if (t < 2097152) {            // x region: 16777216/8 threads
        src = (const float4*)x;  dst = xb;  off4 = t * 2;
    } else {                      // blocks region
        src = (const float4*)blocks;  dst = bb;  off4 = (t - 2097152) * 2;
    }
    float4 a = src[off4];
    float4 b = src[off4 + 1];
    u16x8 v;
    v[0] = f2bf(a.x); v[1] = f2bf(a.y); v[2] = f2bf(a.z); v[3] = f2bf(a.w);
    v[4] = f2bf(b.x); v[5] = f2bf(b.y); v[6] = f2bf(b.z); v[7] = f2bf(b.w);
    *(u16x8*)(dst + off4 * 4) = v;
}

// --- prep: deterministic CSR: blocks sorted by row_idx, payload (k<<6)|ci --
__global__ void bsl_build_csr(const int* __restrict__ row_idx,
                              const int* __restrict__ col_idx,
                              int* __restrict__ csr_off,
                              int* __restrict__ csr_pk) {
    __shared__ int rb_s[K_BLOCKS];
    int t = threadIdx.x;           // 1024 threads
    rb_s[t] = row_idx[t];
    __syncthreads();
    int my_rb = rb_s[t];
    int before = 0, rank = 0;
    for (int j = 0; j < K_BLOCKS; ++j) {
        int r = rb_s[j];
        before += (r < my_rb) ? 1 : 0;
        rank   += (j < t && r == my_rb) ? 1 : 0;
    }
    csr_pk[before + rank] = (t << 6) | col_idx[t];
    if (t < 64) {
        int cnt = 0;
        for (int j = 0; j < K_BLOCKS; ++j) cnt += (rb_s[j] < t) ? 1 : 0;
        csr_off[t] = cnt;
    }
    if (t == 64) csr_off[64] = K_BLOCKS;
}

// --- main: per (n-tile, row-block) MFMA accumulation ------------------------
// LDS 16B-slot swizzle: phys_slot(row, cc) = row*8 + (cc ^ (row&7)),
// cc = col/8 in [0,8). Compatible with global_load_lds placement
// (wave-uniform base + lane*16) because staging chunk ch covers rows
// [ch*8, ch*8+8) and lane l maps to (row = ch*8 + l/8, cc = (l&7)^(l/8 & 7)).
__global__ __launch_bounds__(256, 2) void bsl_main(
    const unsigned short* __restrict__ xb,   // [4096][4096] bf16
    const unsigned short* __restrict__ blk,  // [1024][64][64] bf16
    const float* __restrict__ bias,
    const int* __restrict__ csr_off,
    const int* __restrict__ csr_pk,
    float* __restrict__ y) {
    __shared__ unsigned short a_lds[NT * 64];   // 32 KB
    __shared__ unsigned short b_lds[64 * 64];   // 8 KB

    const int tid = threadIdx.x;
    const int w = tid >> 6;        // wave 0..3 -> rows [w*64, w*64+64)
    const int l = tid & 63;
    const int m = l & 15;          // MFMA row/col-in-tile lane coord
    const int q = l >> 4;          // quad
    const int nt = blockIdx.x;     // 16 n-tiles
    const int rb = blockIdx.y;     // 64 row-blocks
    const int n0 = nt * NT;
    const int k0 = csr_off[rb];
    const int k1 = csr_off[rb + 1];

    // staging lane constants
    const int srow = l >> 3;                    // 0..7
    const int scc  = (l & 7) ^ (srow & 7);      // logical col-chunk this lane fetches
    const int scol = scc * 8;

    f32x4 acc[4][4];
#pragma unroll
    for (int r = 0; r < 4; ++r)
#pragma unroll
        for (int c = 0; c < 4; ++c) acc[r][c] = (f32x4){0.f, 0.f, 0.f, 0.f};

    const int xorv = m & 7;        // read-side swizzle (row&7 == m&7 for all frags)

    for (int kk = k0; kk < k1; ++kk) {
        const int pk = csr_pk[kk];
        const int k  = pk >> 6;
        const int ci = pk & 63;

        // stage A tile: 256x64 bf16 = 32 chunks of 1KB; wave w does chunks i*4+w
        const unsigned short* xrow = xb + (size_t)(n0 + srow) * IN_DIM + ci * 64 + scol;
#pragma unroll
        for (int i = 0; i < 8; ++i) {
            const int ch = i * 4 + w;
            async_copy16(xrow + (size_t)(ch * 8) * IN_DIM, a_lds + ch * 512);
        }
        // stage B tile: 64x64 bf16 = 8 chunks; wave w does chunks w, w+4
        const unsigned short* brow = blk + (size_t)k * 4096 + srow * 64 + scol;
#pragma unroll
        for (int i = 0; i < 2; ++i) {
            const int ch = i * 4 + w;
            async_copy16(brow + ch * 512, b_lds + ch * 512);
        }
        __syncthreads();   // drains vmcnt (global_load_lds) + barrier

#pragma unroll
        for (int s = 0; s < 2; ++s) {
            bf16x8 af[4], bf[4];
            const int cc = (s * 4 + q) ^ xorv;
#pragma unroll
            for (int r = 0; r < 4; ++r) {
                const int row = w * 64 + r * 16 + m;
                af[r] = *(const bf16x8*)(a_lds + row * 64 + cc * 8);
            }
#pragma unroll
            for (int c = 0; c < 4; ++c) {
                const int row = c * 16 + m;
                bf[c] = *(const bf16x8*)(b_lds + row * 64 + cc * 8);
            }
#pragma unroll
            for (int r = 0; r < 4; ++r)
#pragma unroll
                for (int c = 0; c < 4; ++c)
                    acc[r][c] = __builtin_amdgcn_mfma_f32_16x16x32_bf16(
                        af[r], bf[c], acc[r][c], 0, 0, 0);
        }
        __syncthreads();   // protect LDS before next staging
    }

    // epilogue: C/D layout col=lane&15, row=q*4+reg
    const int colbase = rb * 64;
#pragma unroll
    for (int c = 0; c < 4; ++c) {
        const float bv = bias[colbase + c * 16 + m];
#pragma unroll
        for (int r = 0; r < 4; ++r) {
            const int rowb = n0 + w * 64 + r * 16 + q * 4;
#pragma unroll
            for (int e = 0; e < 4; ++e) {
                y[(size_t)(rowb + e) * OUT_DIM + colbase + c * 16 + m] =
                    acc[r][c][e] + bv;
            }
        }
    }
}

// ---------------------------------------------------------------------------
extern "C" void kernel_launch(void* const* d_in, const int* in_sizes, int n_in,
                              void* d_out, int out_size, void* d_ws, size_t ws_size,
                              hipStream_t stream) {
    const float* x      = (const float*)d_in[0];
    const float* blocks = (const float*)d_in[1];
    const float* bias   = (const float*)d_in[2];
    const int* row_idx  = (const int*)d_in[3];
    const int* col_idx  = (const int*)d_in[4];
    float* y = (float*)d_out;

    // ws layout: x_bf16 (32MB) | blocks_bf16 (8MB) | csr_off (128 ints) | csr_pk (1024 ints)
    unsigned short* xb = (unsigned short*)d_ws;
    unsigned short* bb = xb + (size_t)N_ROWS * IN_DIM;
    int* csr_off = (int*)((char*)d_ws + 41943040u);
    int* csr_pk  = csr_off + 128;
    if (ws_size < 41943040u + 8192u) return;  // insufficient scratch (unexpected)

    hipLaunchKernelGGL(bsl_convert, dim3(10240), dim3(256), 0, stream,
                       x, blocks, xb, bb);
    hipLaunchKernelGGL(bsl_build_csr, dim3(1), dim3(1024), 0, stream,
                       row_idx, col_idx, csr_off, csr_pk);
    hipLaunchKernelGGL(bsl_main, dim3(16, 64), dim3(256), 0, stream,
                       xb, bb, bias, csr_off, csr_pk, y);
}

// Round 2
// 182.476 us; speedup vs baseline: 1.2866x; 1.2866x over previous
//
#include <hip/hip_runtime.h>

// ---------------------------------------------------------------------------
// Block-sparse linear  y = x @ W^T + bias  on MI355X (gfx950)
// Round 2: (a) parallel CSR build (LDS atomics), (b) load-balanced schedule:
// row-blocks sorted by block count, paired rank i with rank 63-i so every
// workgroup does ~identical work (fixes the 1.9x makespan imbalance seen in
// round 1: Occupancy 19.6%, MfmaUtil 21%). NT=128 so 32x32 grid = 1024 blocks
// at 24KB LDS = 4 blocks/CU, all co-resident with uniform work.
// ---------------------------------------------------------------------------

typedef __attribute__((ext_vector_type(8))) short bf16x8;   // MFMA A/B frag
typedef __attribute__((ext_vector_type(8))) unsigned short u16x8;
typedef __attribute__((ext_vector_type(4))) float f32x4;     // MFMA C/D frag

#define N_ROWS 4096
#define IN_DIM 4096
#define OUT_DIM 4096
#define BS 64
#define K_BLOCKS 1024
#define NT 128            // rows per workgroup tile
#define PK_STRIDE 256     // max blocks per row-block we store (>> realistic max ~35)

// fp32 -> bf16 round-to-nearest-even
__device__ static inline unsigned short f2bf(float f) {
    unsigned u = __float_as_uint(f);
    u += 0x7FFFu + ((u >> 16) & 1u);
    return (unsigned short)(u >> 16);
}

__device__ static inline void async_copy16(const void* g, void* l) {
    __builtin_amdgcn_global_load_lds(
        (const __attribute__((address_space(1))) void*)g,
        (__attribute__((address_space(3))) void*)l, 16, 0, 0);
}

// --- prep: convert x (16M f32) and blocks (4M f32) to bf16 -----------------
__global__ void bsl_convert(const float* __restrict__ x,
                            const float* __restrict__ blocks,
                            unsigned short* __restrict__ xb,
                            unsigned short* __restrict__ bb) {
    long t = (long)blockIdx.x * 256 + threadIdx.x;   // 0 .. 2621439 (8 floats each)
    const float4* src;
    unsigned short* dst;
    long off4;
    if (t < 2097152) {            // x region
        src = (const float4*)x;  dst = xb;  off4 = t * 2;
    } else {                      // blocks region
        src = (const float4*)blocks;  dst = bb;  off4 = (t - 2097152) * 2;
    }
    float4 a = src[off4];
    float4 b = src[off4 + 1];
    u16x8 v;
    v[0] = f2bf(a.x); v[1] = f2bf(a.y); v[2] = f2bf(a.z); v[3] = f2bf(a.w);
    v[4] = f2bf(b.x); v[5] = f2bf(b.y); v[6] = f2bf(b.z); v[7] = f2bf(b.w);
    *(u16x8*)(dst + off4 * 4) = v;
}

// --- prep: parallel CSR + balanced pair schedule ---------------------------
// counts[rb], csr_pk[rb*PK_STRIDE + rank] = (k<<6)|ci  (rank via LDS atomic;
// order nondeterministic but fp32-sum-order only -> well within tolerance),
// sched[p*2 + {0,1}] = row-blocks ranked p and 63-p by descending count.
__global__ void bsl_build_csr(const int* __restrict__ row_idx,
                              const int* __restrict__ col_idx,
                              int* __restrict__ counts,
                              int* __restrict__ sched,
                              int* __restrict__ csr_pk) {
    __shared__ int cnt_s[64];
    __shared__ int sorted_s[64];
    const int t = threadIdx.x;          // 1024 threads
    if (t < 64) cnt_s[t] = 0;
    __syncthreads();
    const int r = row_idx[t];
    const int rank = atomicAdd(&cnt_s[r], 1);
    if (rank < PK_STRIDE) csr_pk[r * PK_STRIDE + rank] = (t << 6) | col_idx[t];
    __syncthreads();
    if (t < 64) {
        const int mc = cnt_s[t];
        counts[t] = mc;
        int pos = 0;
        for (int j = 0; j < 64; ++j) {
            const int cj = cnt_s[j];
            pos += (cj > mc || (cj == mc && j < t)) ? 1 : 0;
        }
        sorted_s[pos] = t;
    }
    __syncthreads();
    if (t < 32) {
        sched[t * 2]     = sorted_s[t];
        sched[t * 2 + 1] = sorted_s[63 - t];
    }
}

// --- main: per (n-tile, rb-pair) MFMA accumulation -------------------------
// LDS 16B-slot swizzle: phys_slot(row, cc) = row*8 + (cc ^ (row&7)); staging
// lane l in chunk ch maps to (row = ch*8 + l/8, cc = (l&7)^(l/8)), read side
// xors with m&7 (all fragment rows have row&7 == m&7). Verified 0 bank
// conflicts in round 1.
__global__ __launch_bounds__(256, 4) void bsl_main(
    const unsigned short* __restrict__ xb,   // [4096][4096] bf16
    const unsigned short* __restrict__ blk,  // [1024][64][64] bf16
    const float* __restrict__ bias,
    const int* __restrict__ counts,
    const int* __restrict__ sched,
    const int* __restrict__ csr_pk,
    float* __restrict__ y) {
    __shared__ unsigned short a_lds[NT * 64];   // 16 KB
    __shared__ unsigned short b_lds[64 * 64];   // 8 KB

    const int tid = threadIdx.x;
    const int w = tid >> 6;        // wave 0..3 -> rows [w*32, w*32+32)
    const int l = tid & 63;
    const int m = l & 15;          // MFMA lane coord
    const int q = l >> 4;          // quad
    const int nt = blockIdx.x;     // 32 n-tiles of 128 rows
    const int p  = blockIdx.y;     // 32 pairs
    const int n0 = nt * NT;

    // staging lane constants
    const int srow = l >> 3;                    // 0..7
    const int scc  = (l & 7) ^ srow;            // swizzled col-chunk
    const int scol = scc * 8;
    const int xorv = m & 7;                     // read-side swizzle

    for (int half = 0; half < 2; ++half) {
        const int rb  = sched[p * 2 + half];
        const int cnt = counts[rb];

        f32x4 acc[2][4];
#pragma unroll
        for (int r = 0; r < 2; ++r)
#pragma unroll
            for (int c = 0; c < 4; ++c) acc[r][c] = (f32x4){0.f, 0.f, 0.f, 0.f};

        for (int kk = 0; kk < cnt; ++kk) {
            const int pk = csr_pk[rb * PK_STRIDE + kk];
            const int k  = pk >> 6;
            const int ci = pk & 63;

            // stage A tile: 128x64 bf16 = 16 chunks of 1KB; wave w: chunks i*4+w
            const unsigned short* xrow =
                xb + (size_t)(n0 + srow) * IN_DIM + ci * 64 + scol;
#pragma unroll
            for (int i = 0; i < 4; ++i) {
                const int ch = i * 4 + w;
                async_copy16(xrow + (size_t)(ch * 8) * IN_DIM, a_lds + ch * 512);
            }
            // stage B tile: 64x64 bf16 = 8 chunks; wave w: chunks w, w+4
            const unsigned short* brow =
                blk + (size_t)k * 4096 + srow * 64 + scol;
#pragma unroll
            for (int i = 0; i < 2; ++i) {
                const int ch = i * 4 + w;
                async_copy16(brow + ch * 512, b_lds + ch * 512);
            }
            __syncthreads();   // drains vmcnt (global_load_lds) + barrier

#pragma unroll
            for (int s = 0; s < 2; ++s) {
                bf16x8 af[2], bf[4];
                const int cc = (s * 4 + q) ^ xorv;
#pragma unroll
                for (int r = 0; r < 2; ++r) {
                    const int row = w * 32 + r * 16 + m;
                    af[r] = *(const bf16x8*)(a_lds + row * 64 + cc * 8);
                }
#pragma unroll
                for (int c = 0; c < 4; ++c) {
                    const int row = c * 16 + m;
                    bf[c] = *(const bf16x8*)(b_lds + row * 64 + cc * 8);
                }
#pragma unroll
                for (int r = 0; r < 2; ++r)
#pragma unroll
                    for (int c = 0; c < 4; ++c)
                        acc[r][c] = __builtin_amdgcn_mfma_f32_16x16x32_bf16(
                            af[r], bf[c], acc[r][c], 0, 0, 0);
            }
            __syncthreads();   // protect LDS before next staging
        }

        // epilogue: C/D layout col=lane&15, row=q*4+reg
        const int colbase = rb * 64;
#pragma unroll
        for (int c = 0; c < 4; ++c) {
            const float bv = bias[colbase + c * 16 + m];
#pragma unroll
            for (int r = 0; r < 2; ++r) {
                const int rowb = n0 + w * 32 + r * 16 + q * 4;
#pragma unroll
                for (int e = 0; e < 4; ++e) {
                    y[(size_t)(rowb + e) * OUT_DIM + colbase + c * 16 + m] =
                        acc[r][c][e] + bv;
                }
            }
        }
    }
}

// ---------------------------------------------------------------------------
extern "C" void kernel_launch(void* const* d_in, const int* in_sizes, int n_in,
                              void* d_out, int out_size, void* d_ws, size_t ws_size,
                              hipStream_t stream) {
    const float* x      = (const float*)d_in[0];
    const float* blocks = (const float*)d_in[1];
    const float* bias   = (const float*)d_in[2];
    const int* row_idx  = (const int*)d_in[3];
    const int* col_idx  = (const int*)d_in[4];
    float* y = (float*)d_out;

    // ws layout: x_bf16 (32MB) | blocks_bf16 (8MB) | counts(64) | sched(64) |
    //            pad | csr_pk (64*PK_STRIDE ints)
    const size_t base = 41943040u;   // 40 MB
    unsigned short* xb = (unsigned short*)d_ws;
    unsigned short* bb = xb + (size_t)N_ROWS * IN_DIM;
    int* counts = (int*)((char*)d_ws + base);
    int* sched  = counts + 64;
    int* csr_pk = (int*)((char*)d_ws + base + 1024);
    if (ws_size < base + 1024 + (size_t)64 * PK_STRIDE * 4) return;

    hipLaunchKernelGGL(bsl_convert, dim3(10240), dim3(256), 0, stream,
                       x, blocks, xb, bb);
    hipLaunchKernelGGL(bsl_build_csr, dim3(1), dim3(1024), 0, stream,
                       row_idx, col_idx, counts, sched, csr_pk);
    hipLaunchKernelGGL(bsl_main, dim3(32, 32), dim3(256), 0, stream,
                       xb, bb, bias, counts, sched, csr_pk, y);
}